// Round 14
// baseline (414.950 us; speedup 1.0000x reference)
//
#include <hip/hip_runtime.h>

typedef unsigned short u16;
typedef __bf16 bf16x8 __attribute__((ext_vector_type(8)));
typedef float f32x4 __attribute__((ext_vector_type(4)));

#define QSCALE 0.18033688011112042f  // 0.125 * log2(e)

__device__ __forceinline__ float b2f(u16 x) {
    unsigned int u = ((unsigned int)x) << 16;
    return __builtin_bit_cast(float, u);
}
__device__ __forceinline__ u16 f2bf(float f) {
    unsigned int u = __builtin_bit_cast(unsigned int, f);
    u += 0x7fffu + ((u >> 16) & 1u);
    return (u16)(u >> 16);
}
__device__ __forceinline__ void lds_load16(const u16* g, u16* l) {
    __builtin_amdgcn_global_load_lds(
        (const __attribute__((address_space(1))) void*)g,
        (__attribute__((address_space(3))) void*)l, 16, 0, 0);
}

// ---------------------------------------------------------------------------
// One-shot preamble: all weight transposes (fp32->bf16) + rel cvt + bias concat.
// blocks 0..4095:    wq/wk/wv/wo 1024x1024 transposes (z = bid>>10)
// blocks 4096..8191: w1 [1024][4096] -> w1T [4096][1024]
// blocks 8192..12287: w2 [4096][1024] -> w2T [1024][4096]
// blocks 12288..12352: relb cvt (257*64)
// blocks 12353..12364: bqkv concat (3072)
__global__ void prep_kernel(
    const float* __restrict__ wq, const float* __restrict__ wk,
    const float* __restrict__ wv, const float* __restrict__ wo,
    const float* __restrict__ w1, const float* __restrict__ w2,
    const float* __restrict__ rel,
    const float* __restrict__ bq, const float* __restrict__ bk,
    const float* __restrict__ bv,
    u16* __restrict__ wqkvT, u16* __restrict__ woT,
    u16* __restrict__ w1T, u16* __restrict__ w2T,
    u16* __restrict__ relb, float* __restrict__ bqkv) {
    int bid = blockIdx.x;
    int tx = threadIdx.x, ty = threadIdx.y;
    if (bid < 12288) {
        __shared__ u16 tile[32][33];
        const float* in;
        u16* out;
        int R, C, bx, by;
        if (bid < 4096) {
            int z = bid >> 10, i = bid & 1023;
            in = (z == 0) ? wq : (z == 1) ? wk : (z == 2) ? wv : wo;
            out = (z < 3) ? wqkvT + (size_t)z * 1024 * 1024 : woT;
            R = 1024; C = 1024;
            bx = (i & 31) * 32; by = (i >> 5) * 32;
        } else if (bid < 8192) {
            int i = bid - 4096;
            in = w1; out = w1T; R = 1024; C = 4096;
            bx = (i & 127) * 32; by = (i >> 7) * 32;
        } else {
            int i = bid - 8192;
            in = w2; out = w2T; R = 4096; C = 1024;
            bx = (i & 31) * 32; by = (i >> 5) * 32;
        }
#pragma unroll
        for (int i = 0; i < 32; i += 8)
            tile[ty + i][tx] = f2bf(in[(size_t)(by + ty + i) * C + bx + tx]);
        __syncthreads();
#pragma unroll
        for (int i = 0; i < 32; i += 8)
            out[(size_t)(bx + ty + i) * R + by + tx] = tile[tx][ty + i];
    } else if (bid < 12353) {
        int i = (bid - 12288) * 256 + ty * 32 + tx;
        if (i < 257 * 64) relb[i] = f2bf(rel[i]);
    } else {
        int i = (bid - 12353) * 256 + ty * 32 + tx;
        if (i < 3072)
            bqkv[i] = (i < 1024) ? bq[i] : (i < 2048 ? bk[i - 1024] : bv[i - 2048]);
    }
}

// batched bf16 transpose: out[z][c][r] = in[(z*1024 + r)*ldin + coloff + c]
__global__ void transpose_v(const u16* __restrict__ in, int ldin, int coloff,
                            u16* __restrict__ out) {
    __shared__ u16 tile[32][33];
    size_t zout = (size_t)blockIdx.z << 20;
    int bx = blockIdx.x * 32, by = blockIdx.y * 32;
    int tx = threadIdx.x, ty = threadIdx.y;
#pragma unroll
    for (int i = 0; i < 32; i += 8)
        tile[ty + i][tx] =
            in[(size_t)(blockIdx.z * 1024 + by + ty + i) * ldin + coloff + bx + tx];
    __syncthreads();
#pragma unroll
    for (int i = 0; i < 32; i += 8)
        out[zout + (size_t)(bx + ty + i) * 1024 + by + tx] = tile[tx][ty + i];
}

// ---------------------------------------------------------------------------
// LayerNorm over 1024 cols; input fp32 (inf) or bf16 (inb); bf16 out
__global__ __launch_bounds__(256) void ln_kernel(
    const u16* __restrict__ inb, const float* __restrict__ inf,
    const float* __restrict__ g, const float* __restrict__ b,
    u16* __restrict__ out) {
    int row = blockIdx.x, t = threadIdx.x;
    size_t base = (size_t)row * 1024 + t * 4;
    float v[4];
    if (inf) {
        float4 f = *(const float4*)(inf + base);
        v[0] = f.x; v[1] = f.y; v[2] = f.z; v[3] = f.w;
    } else {
        uint2 u = *(const uint2*)(inb + base);
        v[0] = b2f((u16)(u.x & 0xffff)); v[1] = b2f((u16)(u.x >> 16));
        v[2] = b2f((u16)(u.y & 0xffff)); v[3] = b2f((u16)(u.y >> 16));
    }
    float s = v[0] + v[1] + v[2] + v[3];
    float q = v[0] * v[0] + v[1] * v[1] + v[2] * v[2] + v[3] * v[3];
#pragma unroll
    for (int m = 1; m < 64; m <<= 1) {
        s += __shfl_xor(s, m);
        q += __shfl_xor(q, m);
    }
    __shared__ float rs[4], rq[4];
    __shared__ float mu_s, rstd_s;
    int w = t >> 6, lane = t & 63;
    if (lane == 0) { rs[w] = s; rq[w] = q; }
    __syncthreads();
    if (t == 0) {
        float S = rs[0] + rs[1] + rs[2] + rs[3];
        float Q2 = rq[0] + rq[1] + rq[2] + rq[3];
        float mu = S * (1.0f / 1024.0f);
        float var = Q2 * (1.0f / 1024.0f) - mu * mu;
        mu_s = mu;
        rstd_s = rsqrtf(var + 1e-5f);
    }
    __syncthreads();
    float mu = mu_s, rstd = rstd_s;
    u16 o[4];
#pragma unroll
    for (int i = 0; i < 4; i++) {
        int col = t * 4 + i;
        o[i] = f2bf((v[i] - mu) * rstd * g[col] + b[col]);
    }
    uint2 pk;
    pk.x = (unsigned)o[0] | ((unsigned)o[1] << 16);
    pk.y = (unsigned)o[2] | ((unsigned)o[3] << 16);
    *(uint2*)(out + base) = pk;
}

// ---------------------------------------------------------------------------
// GEMM BK=64, BN=64, XOR-swizzled LDS (conflict-free b128 reads). 2D grid.
__global__ __launch_bounds__(256) void gemm_bt64(
    const u16* __restrict__ A, int lda,
    const u16* __restrict__ Bt, int ldb,
    const float* __restrict__ bias,
    const float* __restrict__ resid_f32, const u16* __restrict__ resid_bf,
    u16* __restrict__ outb, float* __restrict__ outf, int ldc,
    int K, float oscale, int gelu) {
    constexpr int AU = 16, BU = 8, UPW = (AU + BU) / 4;  // 6 units/wave
    __shared__ __align__(16) u16 As[2][128 * 64];
    __shared__ __align__(16) u16 Bs[2][64 * 64];
    int t = threadIdx.x, w = t >> 6, lane = t & 63;
    int m0 = blockIdx.y * 128, n0 = blockIdx.x * 64;
    int lo = lane & 15, hi = lane >> 4;
    int wr = w >> 1, wc = w & 1;
    f32x4 acc[4][2];
#pragma unroll
    for (int i = 0; i < 4; i++)
#pragma unroll
        for (int j = 0; j < 2; j++) acc[i][j] = (f32x4){0.f, 0.f, 0.f, 0.f};

    auto stage = [&](int k0, int buf) {
#pragma unroll
        for (int uu = 0; uu < UPW; ++uu) {
            int u = w * UPW + uu;
            if (u < AU) {
                int s = u * 64 + lane;
                int row = s >> 3, cg = (lane & 7) ^ (row & 7);
                lds_load16(A + (size_t)(m0 + row) * lda + k0 + cg * 8,
                           &As[buf][u * 512]);
            } else {
                int u2 = u - AU;
                int s = u2 * 64 + lane;
                int row = s >> 3, cg = (lane & 7) ^ (row & 7);
                lds_load16(Bt + (size_t)(n0 + row) * ldb + k0 + cg * 8,
                           &Bs[buf][u2 * 512]);
            }
        }
    };

    int nk = K >> 6;
    stage(0, 0);
    for (int kk = 0; kk < nk; ++kk) {
        __syncthreads();
        if (kk + 1 < nk) stage((kk + 1) << 6, (kk + 1) & 1);
        int buf = kk & 1;
#pragma unroll
        for (int k2 = 0; k2 < 2; ++k2) {
            bf16x8 a[4], bb[2];
#pragma unroll
            for (int i = 0; i < 4; i++) {
                int row = wr * 64 + i * 16 + lo;
                int g = (k2 * 4 + hi) ^ (row & 7);
                a[i] = *(const bf16x8*)&As[buf][row * 64 + g * 8];
            }
#pragma unroll
            for (int j = 0; j < 2; j++) {
                int row = wc * 32 + j * 16 + lo;
                int g = (k2 * 4 + hi) ^ (row & 7);
                bb[j] = *(const bf16x8*)&Bs[buf][row * 64 + g * 8];
            }
#pragma unroll
            for (int i = 0; i < 4; i++)
#pragma unroll
                for (int j = 0; j < 2; j++)
                    acc[i][j] = __builtin_amdgcn_mfma_f32_16x16x32_bf16(a[i], bb[j], acc[i][j], 0, 0, 0);
        }
    }
#pragma unroll
    for (int j = 0; j < 2; j++) {
        int col = n0 + wc * 32 + j * 16 + lo;
        float bv = bias ? bias[col] : 0.f;
#pragma unroll
        for (int i = 0; i < 4; i++) {
            int rbase = m0 + wr * 64 + i * 16 + hi * 4;
#pragma unroll
            for (int r = 0; r < 4; r++) {
                float v = fmaf(acc[i][j][r], oscale, bv);
                if (gelu) v = 0.5f * v * (1.f + erff(v * 0.70710678118654752f));
                size_t ridx = (size_t)(rbase + r) * ldc + col;
                if (resid_f32) v += resid_f32[ridx];
                if (resid_bf) v += b2f(resid_bf[ridx]);
                if (outf) outf[ridx] = v;
                if (outb) outb[ridx] = f2bf(v);
            }
        }
    }
}

// ---------------------------------------------------------------------------
// GEMM BM=128, BN=128, BK=64: XOR-swizzled dbuf LDS (64KB).
// Epilogue: bias, optional GELU, optional bf16 residual, bf16 or fp32 out.
__global__ __launch_bounds__(256) void gemm_bt128k64(
    const u16* __restrict__ A, int lda,
    const u16* __restrict__ Bt, int ldb,
    const float* __restrict__ bias, const u16* __restrict__ resid_bf,
    u16* __restrict__ outb, float* __restrict__ outf, int ldc,
    int K, float oscale, int gelu) {
    __shared__ __align__(16) u16 As[2][128 * 64];
    __shared__ __align__(16) u16 Bs[2][128 * 64];
    int t = threadIdx.x, w = t >> 6, lane = t & 63;
    int m0 = blockIdx.y * 128, n0 = blockIdx.x * 128;
    int lo = lane & 15, hi = lane >> 4;
    int wr = w >> 1, wc = w & 1;
    f32x4 acc[4][4];
#pragma unroll
    for (int i = 0; i < 4; i++)
#pragma unroll
        for (int j = 0; j < 4; j++) acc[i][j] = (f32x4){0.f, 0.f, 0.f, 0.f};

    auto stage = [&](int k0, int buf) {
#pragma unroll
        for (int uu = 0; uu < 4; ++uu) {
            int u = w * 4 + uu;
            int s = u * 64 + lane;
            int row = s >> 3, cg = (lane & 7) ^ (row & 7);
            lds_load16(A + (size_t)(m0 + row) * lda + k0 + cg * 8,
                       &As[buf][u * 512]);
        }
#pragma unroll
        for (int uu = 0; uu < 4; ++uu) {
            int u = w * 4 + uu;
            int s = u * 64 + lane;
            int row = s >> 3, cg = (lane & 7) ^ (row & 7);
            lds_load16(Bt + (size_t)(n0 + row) * ldb + k0 + cg * 8,
                       &Bs[buf][u * 512]);
        }
    };

    int nk = K >> 6;
    stage(0, 0);
    for (int kk = 0; kk < nk; ++kk) {
        __syncthreads();
        if (kk + 1 < nk) stage((kk + 1) << 6, (kk + 1) & 1);
        int buf = kk & 1;
#pragma unroll
        for (int k2 = 0; k2 < 2; ++k2) {
            bf16x8 a[4], bb[4];
#pragma unroll
            for (int i = 0; i < 4; i++) {
                int row = wr * 64 + i * 16 + lo;
                int g = (k2 * 4 + hi) ^ (row & 7);
                a[i] = *(const bf16x8*)&As[buf][row * 64 + g * 8];
            }
#pragma unroll
            for (int j = 0; j < 4; j++) {
                int row = wc * 64 + j * 16 + lo;
                int g = (k2 * 4 + hi) ^ (row & 7);
                bb[j] = *(const bf16x8*)&Bs[buf][row * 64 + g * 8];
            }
#pragma unroll
            for (int i = 0; i < 4; i++)
#pragma unroll
                for (int j = 0; j < 4; j++)
                    acc[i][j] = __builtin_amdgcn_mfma_f32_16x16x32_bf16(a[i], bb[j], acc[i][j], 0, 0, 0);
        }
    }
#pragma unroll
    for (int j = 0; j < 4; j++) {
        int col = n0 + wc * 64 + j * 16 + lo;
        float bv = bias ? bias[col] : 0.f;
#pragma unroll
        for (int i = 0; i < 4; i++) {
            int rbase = m0 + wr * 64 + i * 16 + hi * 4;
#pragma unroll
            for (int r = 0; r < 4; r++) {
                float v = fmaf(acc[i][j][r], oscale, bv);
                if (gelu) v = 0.5f * v * (1.f + erff(v * 0.70710678118654752f));
                size_t ridx = (size_t)(rbase + r) * ldc + col;
                if (resid_bf) v += b2f(resid_bf[ridx]);
                if (outf) outf[ridx] = v;
                if (outb) outb[ridx] = f2bf(v);
            }
        }
    }
}

// ---------------------------------------------------------------------------
// Flash attention, non-online softmax in log2 domain, rel-bias fused.
// QKV: [4096][3072]; Vtg: [bb][d][s]; relb: [272][64] bf16 (rows 257+ unread).
__global__ __launch_bounds__(256) void attn_kernel(
    const u16* __restrict__ QKV, const u16* __restrict__ Vtg,
    const u16* __restrict__ relb, u16* __restrict__ Ob) {
    __shared__ __align__(16) u16 KsL[2][4096];
    __shared__ __align__(16) u16 VsL[2][4096];
    __shared__ __align__(16) u16 Ps[4][16 * 72];
    __shared__ __align__(16) u16 Rb[4][16 * 280];
    int t = threadIdx.x, w = t >> 6, lane = t & 63;
    int bid = blockIdx.x;
    int qblk = bid & 15, h = (bid >> 4) & 15, bb = bid >> 8;
    int lo = lane & 15, hi = lane >> 4;
    int q0b = qblk * 64;
    int q0 = q0b + w * 16;

    const u16* qrow = QKV + ((size_t)(bb * 1024 + q0 + lo) * 3072 + h * 64 + hi * 8);
    bf16x8 qf0 = *(const bf16x8*)qrow;
    bf16x8 qf1 = *(const bf16x8*)(qrow + 32);

    const u16* Kg = QKV + 1024 + ((size_t)(bb * 1024)) * 3072 + h * 64;
    const u16* Vg = Vtg + ((size_t)(bb * 1024 + h * 64)) * 1024;

    auto stage = [&](int k0, int buf) {
#pragma unroll
        for (int half = 0; half < 2; ++half) {
            int s = half * 256 + w * 64 + lane;
            int row = s >> 3, cg = (s & 7) ^ (row & 7);
            lds_load16(Kg + (size_t)(k0 + row) * 3072 + cg * 8,
                       &KsL[buf][(half * 256 + w * 64) * 8]);
            lds_load16(Vg + (size_t)row * 1024 + k0 + cg * 8,
                       &VsL[buf][(half * 256 + w * 64) * 8]);
        }
    };

    stage(0, 0);  // chunk-0 DMA in flight while we compute R below

    // R = (Q @ rel^T)*QSCALE - 16, wave-private rows hi*4+r, cols pt*16+lo
#pragma unroll 4
    for (int pt = 0; pt < 17; ++pt) {
        bf16x8 rf0 = *(const bf16x8*)&relb[(pt * 16 + lo) * 64 + hi * 8];
        bf16x8 rf1 = *(const bf16x8*)&relb[(pt * 16 + lo) * 64 + 32 + hi * 8];
        f32x4 cz = (f32x4){0.f, 0.f, 0.f, 0.f};
        cz = __builtin_amdgcn_mfma_f32_16x16x32_bf16(qf0, rf0, cz, 0, 0, 0);
        cz = __builtin_amdgcn_mfma_f32_16x16x32_bf16(qf1, rf1, cz, 0, 0, 0);
#pragma unroll
        for (int r = 0; r < 4; r++)
            Rb[w][(hi * 4 + r) * 280 + pt * 16 + lo] =
                f2bf(fmaf(cz[r], QSCALE, -16.0f));
    }
    float blo[4], bhi[4];
#pragma unroll
    for (int r = 0; r < 4; r++) {
        blo[r] = b2f(Rb[w][(hi * 4 + r) * 280]);
        bhi[r] = b2f(Rb[w][(hi * 4 + r) * 280 + 256]);
    }

    f32x4 oacc[4];
#pragma unroll
    for (int j = 0; j < 4; j++) oacc[j] = (f32x4){0.f, 0.f, 0.f, 0.f};
    float l_[4] = {0.f, 0.f, 0.f, 0.f};

    for (int c = 0; c < 16; ++c) {
        int k0 = c * 64;
        __syncthreads();
        if (c < 15) stage(k0 + 64, (c + 1) & 1);
        const u16* Ksb = KsL[c & 1];
        const u16* Vsb = VsL[c & 1];

        f32x4 sc[4];
#pragma unroll
        for (int kt = 0; kt < 4; kt++) {
            int row = kt * 16 + lo, rx = row & 7;
            bf16x8 kf0 = *(const bf16x8*)&Ksb[(row * 8 + (hi ^ rx)) * 8];
            bf16x8 kf1 = *(const bf16x8*)&Ksb[(row * 8 + ((4 + hi) ^ rx)) * 8];
            f32x4 zz = (f32x4){0.f, 0.f, 0.f, 0.f};
            sc[kt] = __builtin_amdgcn_mfma_f32_16x16x32_bf16(qf0, kf0, zz, 0, 0, 0);
            sc[kt] = __builtin_amdgcn_mfma_f32_16x16x32_bf16(qf1, kf1, sc[kt], 0, 0, 0);
        }
        float bt[4][4];
        if (k0 + 192 <= q0b) {
#pragma unroll
            for (int kt = 0; kt < 4; kt++)
#pragma unroll
                for (int r = 0; r < 4; r++) bt[kt][r] = blo[r];
        } else if (k0 >= q0b + 192) {
#pragma unroll
            for (int kt = 0; kt < 4; kt++)
#pragma unroll
                for (int r = 0; r < 4; r++) bt[kt][r] = bhi[r];
        } else {
#pragma unroll
            for (int kt = 0; kt < 4; kt++)
#pragma unroll
                for (int r = 0; r < 4; r++) {
                    int lq = hi * 4 + r;
                    int p = (k0 + kt * 16 + lo) - (q0 + lq);
                    p = p < -128 ? -128 : (p > 128 ? 128 : p);
                    p += 128;
                    bt[kt][r] = b2f(Rb[w][lq * 280 + p]);
                }
        }
#pragma unroll
        for (int kt = 0; kt < 4; kt++)
#pragma unroll
            for (int r = 0; r < 4; r++) {
                float s = fmaf(sc[kt][r], QSCALE, bt[kt][r]);
                float p = __builtin_amdgcn_exp2f(s);
                l_[r] += p;
                Ps[w][(hi * 4 + r) * 72 + kt * 16 + lo] =
                    (u16)(__builtin_bit_cast(unsigned int, p) >> 16);
            }
        bf16x8 pf0 = *(const bf16x8*)&Ps[w][lo * 72 + 8 * hi];
        bf16x8 pf1 = *(const bf16x8*)&Ps[w][lo * 72 + 32 + 8 * hi];
#pragma unroll
        for (int j = 0; j < 4; j++) {
            int row = j * 16 + lo, rx = row & 7;
            bf16x8 vf0 = *(const bf16x8*)&Vsb[(row * 8 + (hi ^ rx)) * 8];
            bf16x8 vf1 = *(const bf16x8*)&Vsb[(row * 8 + ((4 + hi) ^ rx)) * 8];
            oacc[j] = __builtin_amdgcn_mfma_f32_16x16x32_bf16(pf0, vf0, oacc[j], 0, 0, 0);
            oacc[j] = __builtin_amdgcn_mfma_f32_16x16x32_bf16(pf1, vf1, oacc[j], 0, 0, 0);
        }
    }
#pragma unroll
    for (int r = 0; r < 4; r++) {
#pragma unroll
        for (int m = 1; m < 16; m <<= 1) l_[r] += __shfl_xor(l_[r], m);
    }
#pragma unroll
    for (int r = 0; r < 4; r++) {
        float inv = 1.f / l_[r];
        int q = q0 + hi * 4 + r;
#pragma unroll
        for (int j = 0; j < 4; j++)
            Ob[(size_t)(bb * 1024 + q) * 1024 + h * 64 + j * 16 + lo] =
                f2bf(oacc[j][r] * inv);
    }
}

// ---------------------------------------------------------------------------
extern "C" void kernel_launch(void* const* d_in, const int* in_sizes, int n_in,
                              void* d_out, int out_size, void* d_ws, size_t ws_size,
                              hipStream_t stream) {
    const float* x   = (const float*)d_in[0];
    const float* wq  = (const float*)d_in[1];
    const float* bq  = (const float*)d_in[2];
    const float* wk  = (const float*)d_in[3];
    const float* bk  = (const float*)d_in[4];
    const float* wv  = (const float*)d_in[5];
    const float* bv  = (const float*)d_in[6];
    const float* wo  = (const float*)d_in[7];
    const float* bo  = (const float*)d_in[8];
    const float* rel = (const float*)d_in[9];
    const float* g1  = (const float*)d_in[10];
    const float* be1 = (const float*)d_in[11];
    const float* g2  = (const float*)d_in[12];
    const float* be2 = (const float*)d_in[13];
    const float* w1  = (const float*)d_in[14];
    const float* bf1 = (const float*)d_in[15];
    const float* w2  = (const float*)d_in[16];
    const float* bf2 = (const float*)d_in[17];

    char* ws = (char*)d_ws;
    const size_t MB = 1024ull * 1024ull;
    u16* wqkvT = (u16*)(ws + 0 * MB);    // [3072][1024]: wqT | wkT | wvT
    u16* woT  = (u16*)(ws + 6 * MB);
    u16* w1T  = (u16*)(ws + 8 * MB);     // [4096][1024]
    u16* w2T  = (u16*)(ws + 16 * MB);    // [1024][4096]
    u16* h    = (u16*)(ws + 24 * MB);    // LN1 out, later LN2 out
    u16* QKV  = (u16*)(ws + 32 * MB);    // [4096][3072] = 24MB
    u16* Vtg  = (u16*)(ws + 56 * MB);    // V^T per batch [bb][d][s]
    u16* x2b  = (u16*)(ws + 64 * MB);    // bf16 [4096][1024] = 8MB
    u16* att  = (u16*)(ws + 112 * MB);
    u16* relb = (u16*)(ws + 120 * MB);   // [272][64] bf16 (rows 257+ unread)
    float* bqkv = (float*)(ws + 120 * MB + 128 * 1024);  // 3072 floats
    u16* ff1  = (u16*)(ws + 32 * MB);    // [4096][4096] 32MB aliases QKV+Vtg
    u16* h2   = h;

    dim3 tb(32, 8);
    prep_kernel<<<12365, tb, 0, stream>>>(wq, wk, wv, wo, w1, w2, rel,
                                          bq, bk, bv,
                                          wqkvT, woT, w1T, w2T, relb, bqkv);

    ln_kernel<<<4096, 256, 0, stream>>>(nullptr, x, g1, be1, h);

    // fused QKV projection: [4096][3072] (BM=128, BN=128, BK=64)
    gemm_bt128k64<<<dim3(24, 32), 256, 0, stream>>>(h, 1024, wqkvT, 1024,
        bqkv, nullptr, QKV, nullptr, 3072, 1024, 1.f, 0);
    // V^T for attention (V = QKV cols 2048..3071)
    transpose_v<<<dim3(32, 32, 4), tb, 0, stream>>>(QKV, 3072, 2048, Vtg);

    // attention with fused rel-bias (computes Q@rel^T per block via MFMA)
    attn_kernel<<<1024, 256, 0, stream>>>(QKV, Vtg, relb, att);

    // x2 = x + attn @ wo + bo   (bf16 out)
    gemm_bt64<<<dim3(16, 32), 256, 0, stream>>>(att, 1024, woT, 1024,
        bo, x, nullptr, x2b, nullptr, 1024, 1024, 1.f, 0);

    ln_kernel<<<4096, 256, 0, stream>>>(x2b, nullptr, g2, be2, h2);

    // ff1 = gelu(h2 @ w1 + b1)  (BM=128, BN=128, BK=64)
    gemm_bt128k64<<<dim3(32, 32), 256, 0, stream>>>(h2, 1024, w1T, 1024,
        bf1, nullptr, ff1, nullptr, 4096, 1024, 1.f, 1);
    // out = x2 + ff1 @ w2 + b2  (BM=128, BN=128, BK=64; bf16 resid, fp32 out)
    gemm_bt128k64<<<dim3(8, 32), 256, 0, stream>>>(ff1, 4096, w2T, 4096,
        bf2, x2b, nullptr, (float*)d_out, 1024, 4096, 1.f, 0);
}

// Round 15
// 395.614 us; speedup vs baseline: 1.0489x; 1.0489x over previous
//
#include <hip/hip_runtime.h>

typedef unsigned short u16;
typedef __bf16 bf16x8 __attribute__((ext_vector_type(8)));
typedef float f32x4 __attribute__((ext_vector_type(4)));

#define QSCALE 0.18033688011112042f  // 0.125 * log2(e)

__device__ __forceinline__ float b2f(u16 x) {
    unsigned int u = ((unsigned int)x) << 16;
    return __builtin_bit_cast(float, u);
}
__device__ __forceinline__ u16 f2bf(float f) {
    unsigned int u = __builtin_bit_cast(unsigned int, f);
    u += 0x7fffu + ((u >> 16) & 1u);
    return (u16)(u >> 16);
}
__device__ __forceinline__ void lds_load16(const u16* g, u16* l) {
    __builtin_amdgcn_global_load_lds(
        (const __attribute__((address_space(1))) void*)g,
        (__attribute__((address_space(3))) void*)l, 16, 0, 0);
}

// ---------------------------------------------------------------------------
// One-shot preamble: all weight transposes (fp32->bf16) + rel cvt + bias concat.
__global__ void prep_kernel(
    const float* __restrict__ wq, const float* __restrict__ wk,
    const float* __restrict__ wv, const float* __restrict__ wo,
    const float* __restrict__ w1, const float* __restrict__ w2,
    const float* __restrict__ rel,
    const float* __restrict__ bq, const float* __restrict__ bk,
    const float* __restrict__ bv,
    u16* __restrict__ wqkvT, u16* __restrict__ woT,
    u16* __restrict__ w1T, u16* __restrict__ w2T,
    u16* __restrict__ relb, float* __restrict__ bqkv) {
    int bid = blockIdx.x;
    int tx = threadIdx.x, ty = threadIdx.y;
    if (bid < 12288) {
        __shared__ u16 tile[32][33];
        const float* in;
        u16* out;
        int R, C, bx, by;
        if (bid < 4096) {
            int z = bid >> 10, i = bid & 1023;
            in = (z == 0) ? wq : (z == 1) ? wk : (z == 2) ? wv : wo;
            out = (z < 3) ? wqkvT + (size_t)z * 1024 * 1024 : woT;
            R = 1024; C = 1024;
            bx = (i & 31) * 32; by = (i >> 5) * 32;
        } else if (bid < 8192) {
            int i = bid - 4096;
            in = w1; out = w1T; R = 1024; C = 4096;
            bx = (i & 127) * 32; by = (i >> 7) * 32;
        } else {
            int i = bid - 8192;
            in = w2; out = w2T; R = 4096; C = 1024;
            bx = (i & 31) * 32; by = (i >> 5) * 32;
        }
#pragma unroll
        for (int i = 0; i < 32; i += 8)
            tile[ty + i][tx] = f2bf(in[(size_t)(by + ty + i) * C + bx + tx]);
        __syncthreads();
#pragma unroll
        for (int i = 0; i < 32; i += 8)
            out[(size_t)(bx + ty + i) * R + by + tx] = tile[tx][ty + i];
    } else if (bid < 12353) {
        int i = (bid - 12288) * 256 + ty * 32 + tx;
        if (i < 257 * 64) relb[i] = f2bf(rel[i]);
    } else {
        int i = (bid - 12353) * 256 + ty * 32 + tx;
        if (i < 3072)
            bqkv[i] = (i < 1024) ? bq[i] : (i < 2048 ? bk[i - 1024] : bv[i - 2048]);
    }
}

// batched bf16 transpose: out[z][c][r] = in[(z*1024 + r)*ldin + coloff + c]
__global__ void transpose_v(const u16* __restrict__ in, int ldin, int coloff,
                            u16* __restrict__ out) {
    __shared__ u16 tile[32][33];
    size_t zout = (size_t)blockIdx.z << 20;
    int bx = blockIdx.x * 32, by = blockIdx.y * 32;
    int tx = threadIdx.x, ty = threadIdx.y;
#pragma unroll
    for (int i = 0; i < 32; i += 8)
        tile[ty + i][tx] =
            in[(size_t)(blockIdx.z * 1024 + by + ty + i) * ldin + coloff + bx + tx];
    __syncthreads();
#pragma unroll
    for (int i = 0; i < 32; i += 8)
        out[zout + (size_t)(bx + ty + i) * 1024 + by + tx] = tile[tx][ty + i];
}

// ---------------------------------------------------------------------------
// LayerNorm over 1024 cols; input fp32 (inf) or bf16 (inb); bf16 out
__global__ __launch_bounds__(256) void ln_kernel(
    const u16* __restrict__ inb, const float* __restrict__ inf,
    const float* __restrict__ g, const float* __restrict__ b,
    u16* __restrict__ out) {
    int row = blockIdx.x, t = threadIdx.x;
    size_t base = (size_t)row * 1024 + t * 4;
    float v[4];
    if (inf) {
        float4 f = *(const float4*)(inf + base);
        v[0] = f.x; v[1] = f.y; v[2] = f.z; v[3] = f.w;
    } else {
        uint2 u = *(const uint2*)(inb + base);
        v[0] = b2f((u16)(u.x & 0xffff)); v[1] = b2f((u16)(u.x >> 16));
        v[2] = b2f((u16)(u.y & 0xffff)); v[3] = b2f((u16)(u.y >> 16));
    }
    float s = v[0] + v[1] + v[2] + v[3];
    float q = v[0] * v[0] + v[1] * v[1] + v[2] * v[2] + v[3] * v[3];
#pragma unroll
    for (int m = 1; m < 64; m <<= 1) {
        s += __shfl_xor(s, m);
        q += __shfl_xor(q, m);
    }
    __shared__ float rs[4], rq[4];
    __shared__ float mu_s, rstd_s;
    int w = t >> 6, lane = t & 63;
    if (lane == 0) { rs[w] = s; rq[w] = q; }
    __syncthreads();
    if (t == 0) {
        float S = rs[0] + rs[1] + rs[2] + rs[3];
        float Q2 = rq[0] + rq[1] + rq[2] + rq[3];
        float mu = S * (1.0f / 1024.0f);
        float var = Q2 * (1.0f / 1024.0f) - mu * mu;
        mu_s = mu;
        rstd_s = rsqrtf(var + 1e-5f);
    }
    __syncthreads();
    float mu = mu_s, rstd = rstd_s;
    u16 o[4];
#pragma unroll
    for (int i = 0; i < 4; i++) {
        int col = t * 4 + i;
        o[i] = f2bf((v[i] - mu) * rstd * g[col] + b[col]);
    }
    uint2 pk;
    pk.x = (unsigned)o[0] | ((unsigned)o[1] << 16);
    pk.y = (unsigned)o[2] | ((unsigned)o[3] << 16);
    *(uint2*)(out + base) = pk;
}

// ---------------------------------------------------------------------------
// GEMM BK=64, BN=64, XOR-swizzled LDS (conflict-free b128 reads). 2D grid.
__global__ __launch_bounds__(256) void gemm_bt64(
    const u16* __restrict__ A, int lda,
    const u16* __restrict__ Bt, int ldb,
    const float* __restrict__ bias,
    const float* __restrict__ resid_f32, const u16* __restrict__ resid_bf,
    u16* __restrict__ outb, float* __restrict__ outf, int ldc,
    int K, float oscale, int gelu) {
    constexpr int AU = 16, BU = 8, UPW = (AU + BU) / 4;  // 6 units/wave
    __shared__ __align__(16) u16 As[2][128 * 64];
    __shared__ __align__(16) u16 Bs[2][64 * 64];
    int t = threadIdx.x, w = t >> 6, lane = t & 63;
    int m0 = blockIdx.y * 128, n0 = blockIdx.x * 64;
    int lo = lane & 15, hi = lane >> 4;
    int wr = w >> 1, wc = w & 1;
    f32x4 acc[4][2];
#pragma unroll
    for (int i = 0; i < 4; i++)
#pragma unroll
        for (int j = 0; j < 2; j++) acc[i][j] = (f32x4){0.f, 0.f, 0.f, 0.f};

    auto stage = [&](int k0, int buf) {
#pragma unroll
        for (int uu = 0; uu < UPW; ++uu) {
            int u = w * UPW + uu;
            if (u < AU) {
                int s = u * 64 + lane;
                int row = s >> 3, cg = (lane & 7) ^ (row & 7);
                lds_load16(A + (size_t)(m0 + row) * lda + k0 + cg * 8,
                           &As[buf][u * 512]);
            } else {
                int u2 = u - AU;
                int s = u2 * 64 + lane;
                int row = s >> 3, cg = (lane & 7) ^ (row & 7);
                lds_load16(Bt + (size_t)(n0 + row) * ldb + k0 + cg * 8,
                           &Bs[buf][u2 * 512]);
            }
        }
    };

    int nk = K >> 6;
    stage(0, 0);
    for (int kk = 0; kk < nk; ++kk) {
        __syncthreads();
        if (kk + 1 < nk) stage((kk + 1) << 6, (kk + 1) & 1);
        int buf = kk & 1;
#pragma unroll
        for (int k2 = 0; k2 < 2; ++k2) {
            bf16x8 a[4], bb[2];
#pragma unroll
            for (int i = 0; i < 4; i++) {
                int row = wr * 64 + i * 16 + lo;
                int g = (k2 * 4 + hi) ^ (row & 7);
                a[i] = *(const bf16x8*)&As[buf][row * 64 + g * 8];
            }
#pragma unroll
            for (int j = 0; j < 2; j++) {
                int row = wc * 32 + j * 16 + lo;
                int g = (k2 * 4 + hi) ^ (row & 7);
                bb[j] = *(const bf16x8*)&Bs[buf][row * 64 + g * 8];
            }
#pragma unroll
            for (int i = 0; i < 4; i++)
#pragma unroll
                for (int j = 0; j < 2; j++)
                    acc[i][j] = __builtin_amdgcn_mfma_f32_16x16x32_bf16(a[i], bb[j], acc[i][j], 0, 0, 0);
        }
    }
#pragma unroll
    for (int j = 0; j < 2; j++) {
        int col = n0 + wc * 32 + j * 16 + lo;
        float bv = bias ? bias[col] : 0.f;
#pragma unroll
        for (int i = 0; i < 4; i++) {
            int rbase = m0 + wr * 64 + i * 16 + hi * 4;
#pragma unroll
            for (int r = 0; r < 4; r++) {
                float v = fmaf(acc[i][j][r], oscale, bv);
                if (gelu) v = 0.5f * v * (1.f + erff(v * 0.70710678118654752f));
                size_t ridx = (size_t)(rbase + r) * ldc + col;
                if (resid_f32) v += resid_f32[ridx];
                if (resid_bf) v += b2f(resid_bf[ridx]);
                if (outf) outf[ridx] = v;
                if (outb) outb[ridx] = f2bf(v);
            }
        }
    }
}

// ---------------------------------------------------------------------------
// GEMM BM=128, BN=128, BK=64: XOR-swizzled dbuf LDS (64KB).
__global__ __launch_bounds__(256) void gemm_bt128k64(
    const u16* __restrict__ A, int lda,
    const u16* __restrict__ Bt, int ldb,
    const float* __restrict__ bias, const u16* __restrict__ resid_bf,
    u16* __restrict__ outb, float* __restrict__ outf, int ldc,
    int K, float oscale, int gelu) {
    __shared__ __align__(16) u16 As[2][128 * 64];
    __shared__ __align__(16) u16 Bs[2][128 * 64];
    int t = threadIdx.x, w = t >> 6, lane = t & 63;
    int m0 = blockIdx.y * 128, n0 = blockIdx.x * 128;
    int lo = lane & 15, hi = lane >> 4;
    int wr = w >> 1, wc = w & 1;
    f32x4 acc[4][4];
#pragma unroll
    for (int i = 0; i < 4; i++)
#pragma unroll
        for (int j = 0; j < 4; j++) acc[i][j] = (f32x4){0.f, 0.f, 0.f, 0.f};

    auto stage = [&](int k0, int buf) {
#pragma unroll
        for (int uu = 0; uu < 4; ++uu) {
            int u = w * 4 + uu;
            int s = u * 64 + lane;
            int row = s >> 3, cg = (lane & 7) ^ (row & 7);
            lds_load16(A + (size_t)(m0 + row) * lda + k0 + cg * 8,
                       &As[buf][u * 512]);
        }
#pragma unroll
        for (int uu = 0; uu < 4; ++uu) {
            int u = w * 4 + uu;
            int s = u * 64 + lane;
            int row = s >> 3, cg = (lane & 7) ^ (row & 7);
            lds_load16(Bt + (size_t)(n0 + row) * ldb + k0 + cg * 8,
                       &Bs[buf][u * 512]);
        }
    };

    int nk = K >> 6;
    stage(0, 0);
    for (int kk = 0; kk < nk; ++kk) {
        __syncthreads();
        if (kk + 1 < nk) stage((kk + 1) << 6, (kk + 1) & 1);
        int buf = kk & 1;
#pragma unroll
        for (int k2 = 0; k2 < 2; ++k2) {
            bf16x8 a[4], bb[4];
#pragma unroll
            for (int i = 0; i < 4; i++) {
                int row = wr * 64 + i * 16 + lo;
                int g = (k2 * 4 + hi) ^ (row & 7);
                a[i] = *(const bf16x8*)&As[buf][row * 64 + g * 8];
            }
#pragma unroll
            for (int j = 0; j < 4; j++) {
                int row = wc * 64 + j * 16 + lo;
                int g = (k2 * 4 + hi) ^ (row & 7);
                bb[j] = *(const bf16x8*)&Bs[buf][row * 64 + g * 8];
            }
#pragma unroll
            for (int i = 0; i < 4; i++)
#pragma unroll
                for (int j = 0; j < 4; j++)
                    acc[i][j] = __builtin_amdgcn_mfma_f32_16x16x32_bf16(a[i], bb[j], acc[i][j], 0, 0, 0);
        }
    }
#pragma unroll
    for (int j = 0; j < 4; j++) {
        int col = n0 + wc * 64 + j * 16 + lo;
        float bv = bias ? bias[col] : 0.f;
#pragma unroll
        for (int i = 0; i < 4; i++) {
            int rbase = m0 + wr * 64 + i * 16 + hi * 4;
#pragma unroll
            for (int r = 0; r < 4; r++) {
                float v = fmaf(acc[i][j][r], oscale, bv);
                if (gelu) v = 0.5f * v * (1.f + erff(v * 0.70710678118654752f));
                size_t ridx = (size_t)(rbase + r) * ldc + col;
                if (resid_bf) v += b2f(resid_bf[ridx]);
                if (outf) outf[ridx] = v;
                if (outb) outb[ridx] = f2bf(v);
            }
        }
    }
}

// ---------------------------------------------------------------------------
// Flash attention, non-online softmax in log2 domain, rel-bias fused.
// QKV: [4096][3072]; Vtg: [bb][d][s]; relb: [272][64] bf16 (rows 257+ unread).
__global__ __launch_bounds__(256) void attn_kernel(
    const u16* __restrict__ QKV, const u16* __restrict__ Vtg,
    const u16* __restrict__ relb, u16* __restrict__ Ob) {
    __shared__ __align__(16) u16 KsL[2][4096];
    __shared__ __align__(16) u16 VsL[2][4096];
    __shared__ __align__(16) u16 Ps[4][16 * 72];
    __shared__ __align__(16) u16 Rb[4][16 * 280];
    int t = threadIdx.x, w = t >> 6, lane = t & 63;
    int bid = blockIdx.x;
    int qblk = bid & 15, h = (bid >> 4) & 15, bb = bid >> 8;
    int lo = lane & 15, hi = lane >> 4;
    int q0b = qblk * 64;
    int q0 = q0b + w * 16;

    const u16* qrow = QKV + ((size_t)(bb * 1024 + q0 + lo) * 3072 + h * 64 + hi * 8);
    bf16x8 qf0 = *(const bf16x8*)qrow;
    bf16x8 qf1 = *(const bf16x8*)(qrow + 32);

    const u16* Kg = QKV + 1024 + ((size_t)(bb * 1024)) * 3072 + h * 64;
    const u16* Vg = Vtg + ((size_t)(bb * 1024 + h * 64)) * 1024;

    auto stage = [&](int k0, int buf) {
#pragma unroll
        for (int half = 0; half < 2; ++half) {
            int s = half * 256 + w * 64 + lane;
            int row = s >> 3, cg = (s & 7) ^ (row & 7);
            lds_load16(Kg + (size_t)(k0 + row) * 3072 + cg * 8,
                       &KsL[buf][(half * 256 + w * 64) * 8]);
            lds_load16(Vg + (size_t)row * 1024 + k0 + cg * 8,
                       &VsL[buf][(half * 256 + w * 64) * 8]);
        }
    };

    stage(0, 0);  // chunk-0 DMA in flight while we compute R below

    // R = (Q @ rel^T)*QSCALE - 16, wave-private rows hi*4+r, cols pt*16+lo
#pragma unroll 4
    for (int pt = 0; pt < 17; ++pt) {
        bf16x8 rf0 = *(const bf16x8*)&relb[(pt * 16 + lo) * 64 + hi * 8];
        bf16x8 rf1 = *(const bf16x8*)&relb[(pt * 16 + lo) * 64 + 32 + hi * 8];
        f32x4 cz = (f32x4){0.f, 0.f, 0.f, 0.f};
        cz = __builtin_amdgcn_mfma_f32_16x16x32_bf16(qf0, rf0, cz, 0, 0, 0);
        cz = __builtin_amdgcn_mfma_f32_16x16x32_bf16(qf1, rf1, cz, 0, 0, 0);
#pragma unroll
        for (int r = 0; r < 4; r++)
            Rb[w][(hi * 4 + r) * 280 + pt * 16 + lo] =
                f2bf(fmaf(cz[r], QSCALE, -16.0f));
    }
    float blo[4], bhi[4];
#pragma unroll
    for (int r = 0; r < 4; r++) {
        blo[r] = b2f(Rb[w][(hi * 4 + r) * 280]);
        bhi[r] = b2f(Rb[w][(hi * 4 + r) * 280 + 256]);
    }

    f32x4 oacc[4];
#pragma unroll
    for (int j = 0; j < 4; j++) oacc[j] = (f32x4){0.f, 0.f, 0.f, 0.f};
    float l_[4] = {0.f, 0.f, 0.f, 0.f};

    for (int c = 0; c < 16; ++c) {
        int k0 = c * 64;
        __syncthreads();
        if (c < 15) stage(k0 + 64, (c + 1) & 1);
        const u16* Ksb = KsL[c & 1];
        const u16* Vsb = VsL[c & 1];

        f32x4 sc[4];
#pragma unroll
        for (int kt = 0; kt < 4; kt++) {
            int row = kt * 16 + lo, rx = row & 7;
            bf16x8 kf0 = *(const bf16x8*)&Ksb[(row * 8 + (hi ^ rx)) * 8];
            bf16x8 kf1 = *(const bf16x8*)&Ksb[(row * 8 + ((4 + hi) ^ rx)) * 8];
            f32x4 zz = (f32x4){0.f, 0.f, 0.f, 0.f};
            sc[kt] = __builtin_amdgcn_mfma_f32_16x16x32_bf16(qf0, kf0, zz, 0, 0, 0);
            sc[kt] = __builtin_amdgcn_mfma_f32_16x16x32_bf16(qf1, kf1, sc[kt], 0, 0, 0);
        }
        float bt[4][4];
        if (k0 + 192 <= q0b) {
#pragma unroll
            for (int kt = 0; kt < 4; kt++)
#pragma unroll
                for (int r = 0; r < 4; r++) bt[kt][r] = blo[r];
        } else if (k0 >= q0b + 192) {
#pragma unroll
            for (int kt = 0; kt < 4; kt++)
#pragma unroll
                for (int r = 0; r < 4; r++) bt[kt][r] = bhi[r];
        } else {
#pragma unroll
            for (int kt = 0; kt < 4; kt++)
#pragma unroll
                for (int r = 0; r < 4; r++) {
                    int lq = hi * 4 + r;
                    int p = (k0 + kt * 16 + lo) - (q0 + lq);
                    p = p < -128 ? -128 : (p > 128 ? 128 : p);
                    p += 128;
                    bt[kt][r] = b2f(Rb[w][lq * 280 + p]);
                }
        }
#pragma unroll
        for (int kt = 0; kt < 4; kt++)
#pragma unroll
            for (int r = 0; r < 4; r++) {
                float s = fmaf(sc[kt][r], QSCALE, bt[kt][r]);
                float p = __builtin_amdgcn_exp2f(s);
                l_[r] += p;
                Ps[w][(hi * 4 + r) * 72 + kt * 16 + lo] =
                    (u16)(__builtin_bit_cast(unsigned int, p) >> 16);
            }
        bf16x8 pf0 = *(const bf16x8*)&Ps[w][lo * 72 + 8 * hi];
        bf16x8 pf1 = *(const bf16x8*)&Ps[w][lo * 72 + 32 + 8 * hi];
#pragma unroll
        for (int j = 0; j < 4; j++) {
            int row = j * 16 + lo, rx = row & 7;
            bf16x8 vf0 = *(const bf16x8*)&Vsb[(row * 8 + (hi ^ rx)) * 8];
            bf16x8 vf1 = *(const bf16x8*)&Vsb[(row * 8 + ((4 + hi) ^ rx)) * 8];
            oacc[j] = __builtin_amdgcn_mfma_f32_16x16x32_bf16(pf0, vf0, oacc[j], 0, 0, 0);
            oacc[j] = __builtin_amdgcn_mfma_f32_16x16x32_bf16(pf1, vf1, oacc[j], 0, 0, 0);
        }
    }
#pragma unroll
    for (int r = 0; r < 4; r++) {
#pragma unroll
        for (int m = 1; m < 16; m <<= 1) l_[r] += __shfl_xor(l_[r], m);
    }
#pragma unroll
    for (int r = 0; r < 4; r++) {
        float inv = 1.f / l_[r];
        int q = q0 + hi * 4 + r;
#pragma unroll
        for (int j = 0; j < 4; j++)
            Ob[(size_t)(bb * 1024 + q) * 1024 + h * 64 + j * 16 + lo] =
                f2bf(oacc[j][r] * inv);
    }
}

// ---------------------------------------------------------------------------
extern "C" void kernel_launch(void* const* d_in, const int* in_sizes, int n_in,
                              void* d_out, int out_size, void* d_ws, size_t ws_size,
                              hipStream_t stream) {
    const float* x   = (const float*)d_in[0];
    const float* wq  = (const float*)d_in[1];
    const float* bq  = (const float*)d_in[2];
    const float* wk  = (const float*)d_in[3];
    const float* bk  = (const float*)d_in[4];
    const float* wv  = (const float*)d_in[5];
    const float* bv  = (const float*)d_in[6];
    const float* wo  = (const float*)d_in[7];
    const float* bo  = (const float*)d_in[8];
    const float* rel = (const float*)d_in[9];
    const float* g1  = (const float*)d_in[10];
    const float* be1 = (const float*)d_in[11];
    const float* g2  = (const float*)d_in[12];
    const float* be2 = (const float*)d_in[13];
    const float* w1  = (const float*)d_in[14];
    const float* bf1 = (const float*)d_in[15];
    const float* w2  = (const float*)d_in[16];
    const float* bf2 = (const float*)d_in[17];

    char* ws = (char*)d_ws;
    const size_t MB = 1024ull * 1024ull;
    u16* wqkvT = (u16*)(ws + 0 * MB);    // [3072][1024]: wqT | wkT | wvT
    u16* woT  = (u16*)(ws + 6 * MB);
    u16* w1T  = (u16*)(ws + 8 * MB);     // [4096][1024]
    u16* w2T  = (u16*)(ws + 16 * MB);    // [1024][4096]
    u16* h    = (u16*)(ws + 24 * MB);    // LN1 out, later LN2 out
    u16* QKV  = (u16*)(ws + 32 * MB);    // [4096][3072] = 24MB
    u16* Vtg  = (u16*)(ws + 56 * MB);    // V^T per batch [bb][d][s]
    u16* x2b  = (u16*)(ws + 64 * MB);    // bf16 [4096][1024] = 8MB
    u16* att  = (u16*)(ws + 112 * MB);
    u16* relb = (u16*)(ws + 120 * MB);   // [272][64] bf16 (rows 257+ unread)
    float* bqkv = (float*)(ws + 120 * MB + 128 * 1024);  // 3072 floats
    u16* ff1  = (u16*)(ws + 32 * MB);    // [4096][4096] 32MB aliases QKV+Vtg
    u16* h2   = h;

    dim3 tb(32, 8);
    prep_kernel<<<12365, tb, 0, stream>>>(wq, wk, wv, wo, w1, w2, rel,
                                          bq, bk, bv,
                                          wqkvT, woT, w1T, w2T, relb, bqkv);

    ln_kernel<<<4096, 256, 0, stream>>>(nullptr, x, g1, be1, h);

    // fused QKV projection: [4096][3072] (BM=128, BN=128, BK=64)
    gemm_bt128k64<<<dim3(24, 32), 256, 0, stream>>>(h, 1024, wqkvT, 1024,
        bqkv, nullptr, QKV, nullptr, 3072, 1024, 1.f, 0);
    // V^T for attention (V = QKV cols 2048..3071)
    transpose_v<<<dim3(32, 32, 4), tb, 0, stream>>>(QKV, 3072, 2048, Vtg);

    // attention with fused rel-bias (computes Q@rel^T per block via MFMA)
    attn_kernel<<<1024, 256, 0, stream>>>(QKV, Vtg, relb, att);

    // x2 = x + attn @ wo + bo   (bf16 out)
    gemm_bt64<<<dim3(16, 32), 256, 0, stream>>>(att, 1024, woT, 1024,
        bo, x, nullptr, x2b, nullptr, 1024, 1024, 1.f, 0);

    ln_kernel<<<4096, 256, 0, stream>>>(x2b, nullptr, g2, be2, h2);

    // ff1 = gelu(h2 @ w1 + b1)  (BM=128, BN=128, BK=64)
    gemm_bt128k64<<<dim3(32, 32), 256, 0, stream>>>(h2, 1024, w1T, 1024,
        bf1, nullptr, ff1, nullptr, 4096, 1024, 1.f, 1);
    // out = x2 + ff1 @ w2 + b2  (BK=64, BN=64: 512 blocks, 2/CU)
    gemm_bt64<<<dim3(16, 32), 256, 0, stream>>>(ff1, 4096, w2T, 4096,
        bf2, nullptr, x2b, nullptr, (float*)d_out, 1024, 4096, 1.f, 0);
}

// Round 16
// 392.280 us; speedup vs baseline: 1.0578x; 1.0085x over previous
//
#include <hip/hip_runtime.h>

typedef unsigned short u16;
typedef __bf16 bf16x8 __attribute__((ext_vector_type(8)));
typedef float f32x4 __attribute__((ext_vector_type(4)));

#define QSCALE 0.18033688011112042f  // 0.125 * log2(e)

__device__ __forceinline__ float b2f(u16 x) {
    unsigned int u = ((unsigned int)x) << 16;
    return __builtin_bit_cast(float, u);
}
__device__ __forceinline__ u16 f2bf(float f) {
    unsigned int u = __builtin_bit_cast(unsigned int, f);
    u += 0x7fffu + ((u >> 16) & 1u);
    return (u16)(u >> 16);
}
__device__ __forceinline__ void lds_load16(const u16* g, u16* l) {
    __builtin_amdgcn_global_load_lds(
        (const __attribute__((address_space(1))) void*)g,
        (__attribute__((address_space(3))) void*)l, 16, 0, 0);
}

// ---------------------------------------------------------------------------
// One-shot preamble: weight transposes (fp32->bf16) + rel cvt + bias concat
// + LN1 (blocks 12365..16460; depends only on x).
__global__ void prep_kernel(
    const float* __restrict__ wq, const float* __restrict__ wk,
    const float* __restrict__ wv, const float* __restrict__ wo,
    const float* __restrict__ w1, const float* __restrict__ w2,
    const float* __restrict__ rel,
    const float* __restrict__ bq, const float* __restrict__ bk,
    const float* __restrict__ bv,
    const float* __restrict__ x, const float* __restrict__ g1,
    const float* __restrict__ be1,
    u16* __restrict__ wqkvT, u16* __restrict__ woT,
    u16* __restrict__ w1T, u16* __restrict__ w2T,
    u16* __restrict__ relb, float* __restrict__ bqkv, u16* __restrict__ h) {
    int bid = blockIdx.x;
    int tx = threadIdx.x, ty = threadIdx.y;
    int t = ty * 32 + tx;
    if (bid < 12288) {
        __shared__ u16 tile[32][33];
        const float* in;
        u16* out;
        int R, C, bx, by;
        if (bid < 4096) {
            int z = bid >> 10, i = bid & 1023;
            in = (z == 0) ? wq : (z == 1) ? wk : (z == 2) ? wv : wo;
            out = (z < 3) ? wqkvT + (size_t)z * 1024 * 1024 : woT;
            R = 1024; C = 1024;
            bx = (i & 31) * 32; by = (i >> 5) * 32;
        } else if (bid < 8192) {
            int i = bid - 4096;
            in = w1; out = w1T; R = 1024; C = 4096;
            bx = (i & 127) * 32; by = (i >> 7) * 32;
        } else {
            int i = bid - 8192;
            in = w2; out = w2T; R = 4096; C = 1024;
            bx = (i & 31) * 32; by = (i >> 5) * 32;
        }
#pragma unroll
        for (int i = 0; i < 32; i += 8)
            tile[ty + i][tx] = f2bf(in[(size_t)(by + ty + i) * C + bx + tx]);
        __syncthreads();
#pragma unroll
        for (int i = 0; i < 32; i += 8)
            out[(size_t)(bx + ty + i) * R + by + tx] = tile[tx][ty + i];
    } else if (bid < 12353) {
        int i = (bid - 12288) * 256 + t;
        if (i < 257 * 64) relb[i] = f2bf(rel[i]);
    } else if (bid < 12365) {
        int i = (bid - 12353) * 256 + t;
        if (i < 3072)
            bqkv[i] = (i < 1024) ? bq[i] : (i < 2048 ? bk[i - 1024] : bv[i - 2048]);
    } else {
        // LayerNorm1 row
        int row = bid - 12365;
        size_t base = (size_t)row * 1024 + t * 4;
        float4 f = *(const float4*)(x + base);
        float v[4] = {f.x, f.y, f.z, f.w};
        float s = v[0] + v[1] + v[2] + v[3];
        float q = v[0] * v[0] + v[1] * v[1] + v[2] * v[2] + v[3] * v[3];
#pragma unroll
        for (int m = 1; m < 64; m <<= 1) {
            s += __shfl_xor(s, m);
            q += __shfl_xor(q, m);
        }
        __shared__ float rs[4], rq[4];
        __shared__ float mu_s, rstd_s;
        int w = t >> 6, lane = t & 63;
        if (lane == 0) { rs[w] = s; rq[w] = q; }
        __syncthreads();
        if (t == 0) {
            float S = rs[0] + rs[1] + rs[2] + rs[3];
            float Q2 = rq[0] + rq[1] + rq[2] + rq[3];
            float mu = S * (1.0f / 1024.0f);
            float var = Q2 * (1.0f / 1024.0f) - mu * mu;
            mu_s = mu;
            rstd_s = rsqrtf(var + 1e-5f);
        }
        __syncthreads();
        float mu = mu_s, rstd = rstd_s;
        u16 o[4];
#pragma unroll
        for (int i = 0; i < 4; i++) {
            int col = t * 4 + i;
            o[i] = f2bf((v[i] - mu) * rstd * g1[col] + be1[col]);
        }
        uint2 pk;
        pk.x = (unsigned)o[0] | ((unsigned)o[1] << 16);
        pk.y = (unsigned)o[2] | ((unsigned)o[3] << 16);
        *(uint2*)(h + base) = pk;
    }
}

// ---------------------------------------------------------------------------
// LayerNorm over 1024 cols; bf16 in, bf16 out (LN2)
__global__ __launch_bounds__(256) void ln_kernel(
    const u16* __restrict__ inb, const float* __restrict__ g,
    const float* __restrict__ b, u16* __restrict__ out) {
    int row = blockIdx.x, t = threadIdx.x;
    size_t base = (size_t)row * 1024 + t * 4;
    float v[4];
    uint2 u = *(const uint2*)(inb + base);
    v[0] = b2f((u16)(u.x & 0xffff)); v[1] = b2f((u16)(u.x >> 16));
    v[2] = b2f((u16)(u.y & 0xffff)); v[3] = b2f((u16)(u.y >> 16));
    float s = v[0] + v[1] + v[2] + v[3];
    float q = v[0] * v[0] + v[1] * v[1] + v[2] * v[2] + v[3] * v[3];
#pragma unroll
    for (int m = 1; m < 64; m <<= 1) {
        s += __shfl_xor(s, m);
        q += __shfl_xor(q, m);
    }
    __shared__ float rs[4], rq[4];
    __shared__ float mu_s, rstd_s;
    int w = t >> 6, lane = t & 63;
    if (lane == 0) { rs[w] = s; rq[w] = q; }
    __syncthreads();
    if (t == 0) {
        float S = rs[0] + rs[1] + rs[2] + rs[3];
        float Q2 = rq[0] + rq[1] + rq[2] + rq[3];
        float mu = S * (1.0f / 1024.0f);
        float var = Q2 * (1.0f / 1024.0f) - mu * mu;
        mu_s = mu;
        rstd_s = rsqrtf(var + 1e-5f);
    }
    __syncthreads();
    float mu = mu_s, rstd = rstd_s;
    u16 o[4];
#pragma unroll
    for (int i = 0; i < 4; i++) {
        int col = t * 4 + i;
        o[i] = f2bf((v[i] - mu) * rstd * g[col] + b[col]);
    }
    uint2 pk;
    pk.x = (unsigned)o[0] | ((unsigned)o[1] << 16);
    pk.y = (unsigned)o[2] | ((unsigned)o[3] << 16);
    *(uint2*)(out + base) = pk;
}

// ---------------------------------------------------------------------------
// GEMM BK=64, BN=64, XOR-swizzled LDS. 2D grid.
__global__ __launch_bounds__(256) void gemm_bt64(
    const u16* __restrict__ A, int lda,
    const u16* __restrict__ Bt, int ldb,
    const float* __restrict__ bias,
    const float* __restrict__ resid_f32, const u16* __restrict__ resid_bf,
    u16* __restrict__ outb, float* __restrict__ outf, int ldc,
    int K, float oscale, int gelu) {
    constexpr int AU = 16, BU = 8, UPW = (AU + BU) / 4;  // 6 units/wave
    __shared__ __align__(16) u16 As[2][128 * 64];
    __shared__ __align__(16) u16 Bs[2][64 * 64];
    int t = threadIdx.x, w = t >> 6, lane = t & 63;
    int m0 = blockIdx.y * 128, n0 = blockIdx.x * 64;
    int lo = lane & 15, hi = lane >> 4;
    int wr = w >> 1, wc = w & 1;
    f32x4 acc[4][2];
#pragma unroll
    for (int i = 0; i < 4; i++)
#pragma unroll
        for (int j = 0; j < 2; j++) acc[i][j] = (f32x4){0.f, 0.f, 0.f, 0.f};

    auto stage = [&](int k0, int buf) {
#pragma unroll
        for (int uu = 0; uu < UPW; ++uu) {
            int u = w * UPW + uu;
            if (u < AU) {
                int s = u * 64 + lane;
                int row = s >> 3, cg = (lane & 7) ^ (row & 7);
                lds_load16(A + (size_t)(m0 + row) * lda + k0 + cg * 8,
                           &As[buf][u * 512]);
            } else {
                int u2 = u - AU;
                int s = u2 * 64 + lane;
                int row = s >> 3, cg = (lane & 7) ^ (row & 7);
                lds_load16(Bt + (size_t)(n0 + row) * ldb + k0 + cg * 8,
                           &Bs[buf][u2 * 512]);
            }
        }
    };

    int nk = K >> 6;
    stage(0, 0);
    for (int kk = 0; kk < nk; ++kk) {
        __syncthreads();
        if (kk + 1 < nk) stage((kk + 1) << 6, (kk + 1) & 1);
        int buf = kk & 1;
#pragma unroll
        for (int k2 = 0; k2 < 2; ++k2) {
            bf16x8 a[4], bb[2];
#pragma unroll
            for (int i = 0; i < 4; i++) {
                int row = wr * 64 + i * 16 + lo;
                int g = (k2 * 4 + hi) ^ (row & 7);
                a[i] = *(const bf16x8*)&As[buf][row * 64 + g * 8];
            }
#pragma unroll
            for (int j = 0; j < 2; j++) {
                int row = wc * 32 + j * 16 + lo;
                int g = (k2 * 4 + hi) ^ (row & 7);
                bb[j] = *(const bf16x8*)&Bs[buf][row * 64 + g * 8];
            }
#pragma unroll
            for (int i = 0; i < 4; i++)
#pragma unroll
                for (int j = 0; j < 2; j++)
                    acc[i][j] = __builtin_amdgcn_mfma_f32_16x16x32_bf16(a[i], bb[j], acc[i][j], 0, 0, 0);
        }
    }
#pragma unroll
    for (int j = 0; j < 2; j++) {
        int col = n0 + wc * 32 + j * 16 + lo;
        float bv = bias ? bias[col] : 0.f;
#pragma unroll
        for (int i = 0; i < 4; i++) {
            int rbase = m0 + wr * 64 + i * 16 + hi * 4;
#pragma unroll
            for (int r = 0; r < 4; r++) {
                float v = fmaf(acc[i][j][r], oscale, bv);
                if (gelu) v = 0.5f * v * (1.f + erff(v * 0.70710678118654752f));
                size_t ridx = (size_t)(rbase + r) * ldc + col;
                if (resid_f32) v += resid_f32[ridx];
                if (resid_bf) v += b2f(resid_bf[ridx]);
                if (outf) outf[ridx] = v;
                if (outb) outb[ridx] = f2bf(v);
            }
        }
    }
}

// ---------------------------------------------------------------------------
// GEMM BM=128, BN=128, BK=64: XOR-swizzled dbuf LDS (64KB).
// If vtg != nullptr and n0 >= 2048 (V columns of fused QKV): the tile is
// written TRANSPOSED to vtg[bb][d][s] via an XOR-swizzled LDS transpose
// (coalesced 16B stores), and the normal outb store is skipped.
__global__ __launch_bounds__(256) void gemm_bt128k64(
    const u16* __restrict__ A, int lda,
    const u16* __restrict__ Bt, int ldb,
    const float* __restrict__ bias, const u16* __restrict__ resid_bf,
    u16* __restrict__ outb, float* __restrict__ outf, int ldc,
    int K, float oscale, int gelu, u16* __restrict__ vtg) {
    __shared__ __align__(16) u16 As[2][128 * 64];
    __shared__ __align__(16) u16 Bs[2][128 * 64];
    int t = threadIdx.x, w = t >> 6, lane = t & 63;
    int m0 = blockIdx.y * 128, n0 = blockIdx.x * 128;
    int lo = lane & 15, hi = lane >> 4;
    int wr = w >> 1, wc = w & 1;
    f32x4 acc[4][4];
#pragma unroll
    for (int i = 0; i < 4; i++)
#pragma unroll
        for (int j = 0; j < 4; j++) acc[i][j] = (f32x4){0.f, 0.f, 0.f, 0.f};

    auto stage = [&](int k0, int buf) {
#pragma unroll
        for (int uu = 0; uu < 4; ++uu) {
            int u = w * 4 + uu;
            int s = u * 64 + lane;
            int row = s >> 3, cg = (lane & 7) ^ (row & 7);
            lds_load16(A + (size_t)(m0 + row) * lda + k0 + cg * 8,
                       &As[buf][u * 512]);
        }
#pragma unroll
        for (int uu = 0; uu < 4; ++uu) {
            int u = w * 4 + uu;
            int s = u * 64 + lane;
            int row = s >> 3, cg = (lane & 7) ^ (row & 7);
            lds_load16(Bt + (size_t)(n0 + row) * ldb + k0 + cg * 8,
                       &Bs[buf][u * 512]);
        }
    };

    int nk = K >> 6;
    stage(0, 0);
    for (int kk = 0; kk < nk; ++kk) {
        __syncthreads();
        if (kk + 1 < nk) stage((kk + 1) << 6, (kk + 1) & 1);
        int buf = kk & 1;
#pragma unroll
        for (int k2 = 0; k2 < 2; ++k2) {
            bf16x8 a[4], bb[4];
#pragma unroll
            for (int i = 0; i < 4; i++) {
                int row = wr * 64 + i * 16 + lo;
                int g = (k2 * 4 + hi) ^ (row & 7);
                a[i] = *(const bf16x8*)&As[buf][row * 64 + g * 8];
            }
#pragma unroll
            for (int j = 0; j < 4; j++) {
                int row = wc * 64 + j * 16 + lo;
                int g = (k2 * 4 + hi) ^ (row & 7);
                bb[j] = *(const bf16x8*)&Bs[buf][row * 64 + g * 8];
            }
#pragma unroll
            for (int i = 0; i < 4; i++)
#pragma unroll
                for (int j = 0; j < 4; j++)
                    acc[i][j] = __builtin_amdgcn_mfma_f32_16x16x32_bf16(a[i], bb[j], acc[i][j], 0, 0, 0);
        }
    }
    if (vtg && n0 >= 2048) {
        // transposed epilogue: acc -> swizzled LDS -> coalesced Vtg stores
        __syncthreads();  // all K-loop ds_reads done; reuse As as transpose buf
        u16* TT = &As[0][0];  // [128 d][128 m], XOR-swizzled
#pragma unroll
        for (int j = 0; j < 4; j++) {
            int coll = wc * 64 + j * 16 + lo;            // local d
            int colg = n0 + coll;
            float bv = bias ? bias[colg] : 0.f;
            int sw = (coll & 15) << 3;
#pragma unroll
            for (int i = 0; i < 4; i++) {
                int ml = wr * 64 + i * 16 + hi * 4;      // local m (s)
                u16 pk[4];
#pragma unroll
                for (int r = 0; r < 4; r++) pk[r] = f2bf(acc[i][j][r] + bv);
                *(unsigned long long*)&TT[coll * 128 + (ml ^ sw)] =
                    *(unsigned long long*)pk;
            }
        }
        __syncthreads();
        int bb2 = m0 >> 10, s0 = m0 & 1023;
        size_t zout = (size_t)bb2 << 20;
#pragma unroll
        for (int pass = 0; pass < 8; ++pass) {
            int idx = pass * 256 + t;
            int drow = idx >> 4, mc = (idx & 15) * 8;
            int sw = (drow & 15) << 3;
            uint4 v4 = *(uint4*)&TT[drow * 128 + (mc ^ sw)];
            *(uint4*)&vtg[zout + (size_t)(n0 - 2048 + drow) * 1024 + s0 + mc] = v4;
        }
        return;
    }
#pragma unroll
    for (int j = 0; j < 4; j++) {
        int col = n0 + wc * 64 + j * 16 + lo;
        float bv = bias ? bias[col] : 0.f;
#pragma unroll
        for (int i = 0; i < 4; i++) {
            int rbase = m0 + wr * 64 + i * 16 + hi * 4;
#pragma unroll
            for (int r = 0; r < 4; r++) {
                float v = fmaf(acc[i][j][r], oscale, bv);
                if (gelu) v = 0.5f * v * (1.f + erff(v * 0.70710678118654752f));
                size_t ridx = (size_t)(rbase + r) * ldc + col;
                if (resid_bf) v += b2f(resid_bf[ridx]);
                if (outf) outf[ridx] = v;
                if (outb) outb[ridx] = f2bf(v);
            }
        }
    }
}

// ---------------------------------------------------------------------------
// Flash attention, non-online softmax in log2 domain, rel-bias fused.
// QKV: [4096][3072] (V cols unused); Vtg: [bb][d][s]; relb: [272][64] bf16.
__global__ __launch_bounds__(256) void attn_kernel(
    const u16* __restrict__ QKV, const u16* __restrict__ Vtg,
    const u16* __restrict__ relb, u16* __restrict__ Ob) {
    __shared__ __align__(16) u16 KsL[2][4096];
    __shared__ __align__(16) u16 VsL[2][4096];
    __shared__ __align__(16) u16 Ps[4][16 * 72];
    __shared__ __align__(16) u16 Rb[4][16 * 280];
    int t = threadIdx.x, w = t >> 6, lane = t & 63;
    int bid = blockIdx.x;
    int qblk = bid & 15, h = (bid >> 4) & 15, bb = bid >> 8;
    int lo = lane & 15, hi = lane >> 4;
    int q0b = qblk * 64;
    int q0 = q0b + w * 16;

    const u16* qrow = QKV + ((size_t)(bb * 1024 + q0 + lo) * 3072 + h * 64 + hi * 8);
    bf16x8 qf0 = *(const bf16x8*)qrow;
    bf16x8 qf1 = *(const bf16x8*)(qrow + 32);

    const u16* Kg = QKV + 1024 + ((size_t)(bb * 1024)) * 3072 + h * 64;
    const u16* Vg = Vtg + ((size_t)(bb * 1024 + h * 64)) * 1024;

    auto stage = [&](int k0, int buf) {
#pragma unroll
        for (int half = 0; half < 2; ++half) {
            int s = half * 256 + w * 64 + lane;
            int row = s >> 3, cg = (s & 7) ^ (row & 7);
            lds_load16(Kg + (size_t)(k0 + row) * 3072 + cg * 8,
                       &KsL[buf][(half * 256 + w * 64) * 8]);
            lds_load16(Vg + (size_t)row * 1024 + k0 + cg * 8,
                       &VsL[buf][(half * 256 + w * 64) * 8]);
        }
    };

    stage(0, 0);  // chunk-0 DMA in flight while we compute R below

    // R = (Q @ rel^T)*QSCALE - 16, wave-private rows hi*4+r, cols pt*16+lo
#pragma unroll 4
    for (int pt = 0; pt < 17; ++pt) {
        bf16x8 rf0 = *(const bf16x8*)&relb[(pt * 16 + lo) * 64 + hi * 8];
        bf16x8 rf1 = *(const bf16x8*)&relb[(pt * 16 + lo) * 64 + 32 + hi * 8];
        f32x4 cz = (f32x4){0.f, 0.f, 0.f, 0.f};
        cz = __builtin_amdgcn_mfma_f32_16x16x32_bf16(qf0, rf0, cz, 0, 0, 0);
        cz = __builtin_amdgcn_mfma_f32_16x16x32_bf16(qf1, rf1, cz, 0, 0, 0);
#pragma unroll
        for (int r = 0; r < 4; r++)
            Rb[w][(hi * 4 + r) * 280 + pt * 16 + lo] =
                f2bf(fmaf(cz[r], QSCALE, -16.0f));
    }
    float blo[4], bhi[4];
#pragma unroll
    for (int r = 0; r < 4; r++) {
        blo[r] = b2f(Rb[w][(hi * 4 + r) * 280]);
        bhi[r] = b2f(Rb[w][(hi * 4 + r) * 280 + 256]);
    }

    f32x4 oacc[4];
#pragma unroll
    for (int j = 0; j < 4; j++) oacc[j] = (f32x4){0.f, 0.f, 0.f, 0.f};
    float l_[4] = {0.f, 0.f, 0.f, 0.f};

    for (int c = 0; c < 16; ++c) {
        int k0 = c * 64;
        __syncthreads();
        if (c < 15) stage(k0 + 64, (c + 1) & 1);
        const u16* Ksb = KsL[c & 1];
        const u16* Vsb = VsL[c & 1];

        f32x4 sc[4];
#pragma unroll
        for (int kt = 0; kt < 4; kt++) {
            int row = kt * 16 + lo, rx = row & 7;
            bf16x8 kf0 = *(const bf16x8*)&Ksb[(row * 8 + (hi ^ rx)) * 8];
            bf16x8 kf1 = *(const bf16x8*)&Ksb[(row * 8 + ((4 + hi) ^ rx)) * 8];
            f32x4 zz = (f32x4){0.f, 0.f, 0.f, 0.f};
            sc[kt] = __builtin_amdgcn_mfma_f32_16x16x32_bf16(qf0, kf0, zz, 0, 0, 0);
            sc[kt] = __builtin_amdgcn_mfma_f32_16x16x32_bf16(qf1, kf1, sc[kt], 0, 0, 0);
        }
        float bt[4][4];
        if (k0 + 192 <= q0b) {
#pragma unroll
            for (int kt = 0; kt < 4; kt++)
#pragma unroll
                for (int r = 0; r < 4; r++) bt[kt][r] = blo[r];
        } else if (k0 >= q0b + 192) {
#pragma unroll
            for (int kt = 0; kt < 4; kt++)
#pragma unroll
                for (int r = 0; r < 4; r++) bt[kt][r] = bhi[r];
        } else {
#pragma unroll
            for (int kt = 0; kt < 4; kt++)
#pragma unroll
                for (int r = 0; r < 4; r++) {
                    int lq = hi * 4 + r;
                    int p = (k0 + kt * 16 + lo) - (q0 + lq);
                    p = p < -128 ? -128 : (p > 128 ? 128 : p);
                    p += 128;
                    bt[kt][r] = b2f(Rb[w][lq * 280 + p]);
                }
        }
#pragma unroll
        for (int kt = 0; kt < 4; kt++)
#pragma unroll
            for (int r = 0; r < 4; r++) {
                float s = fmaf(sc[kt][r], QSCALE, bt[kt][r]);
                float p = __builtin_amdgcn_exp2f(s);
                l_[r] += p;
                Ps[w][(hi * 4 + r) * 72 + kt * 16 + lo] =
                    (u16)(__builtin_bit_cast(unsigned int, p) >> 16);
            }
        bf16x8 pf0 = *(const bf16x8*)&Ps[w][lo * 72 + 8 * hi];
        bf16x8 pf1 = *(const bf16x8*)&Ps[w][lo * 72 + 32 + 8 * hi];
#pragma unroll
        for (int j = 0; j < 4; j++) {
            int row = j * 16 + lo, rx = row & 7;
            bf16x8 vf0 = *(const bf16x8*)&Vsb[(row * 8 + (hi ^ rx)) * 8];
            bf16x8 vf1 = *(const bf16x8*)&Vsb[(row * 8 + ((4 + hi) ^ rx)) * 8];
            oacc[j] = __builtin_amdgcn_mfma_f32_16x16x32_bf16(pf0, vf0, oacc[j], 0, 0, 0);
            oacc[j] = __builtin_amdgcn_mfma_f32_16x16x32_bf16(pf1, vf1, oacc[j], 0, 0, 0);
        }
    }
#pragma unroll
    for (int r = 0; r < 4; r++) {
#pragma unroll
        for (int m = 1; m < 16; m <<= 1) l_[r] += __shfl_xor(l_[r], m);
    }
#pragma unroll
    for (int r = 0; r < 4; r++) {
        float inv = 1.f / l_[r];
        int q = q0 + hi * 4 + r;
#pragma unroll
        for (int j = 0; j < 4; j++)
            Ob[(size_t)(bb * 1024 + q) * 1024 + h * 64 + j * 16 + lo] =
                f2bf(oacc[j][r] * inv);
    }
}

// ---------------------------------------------------------------------------
extern "C" void kernel_launch(void* const* d_in, const int* in_sizes, int n_in,
                              void* d_out, int out_size, void* d_ws, size_t ws_size,
                              hipStream_t stream) {
    const float* x   = (const float*)d_in[0];
    const float* wq  = (const float*)d_in[1];
    const float* bq  = (const float*)d_in[2];
    const float* wk  = (const float*)d_in[3];
    const float* bk  = (const float*)d_in[4];
    const float* wv  = (const float*)d_in[5];
    const float* bv  = (const float*)d_in[6];
    const float* wo  = (const float*)d_in[7];
    const float* bo  = (const float*)d_in[8];
    const float* rel = (const float*)d_in[9];
    const float* g1  = (const float*)d_in[10];
    const float* be1 = (const float*)d_in[11];
    const float* g2  = (const float*)d_in[12];
    const float* be2 = (const float*)d_in[13];
    const float* w1  = (const float*)d_in[14];
    const float* bf1 = (const float*)d_in[15];
    const float* w2  = (const float*)d_in[16];
    const float* bf2 = (const float*)d_in[17];

    char* ws = (char*)d_ws;
    const size_t MB = 1024ull * 1024ull;
    u16* wqkvT = (u16*)(ws + 0 * MB);    // [3072][1024]: wqT | wkT | wvT
    u16* woT  = (u16*)(ws + 6 * MB);
    u16* w1T  = (u16*)(ws + 8 * MB);     // [4096][1024]
    u16* w2T  = (u16*)(ws + 16 * MB);    // [1024][4096]
    u16* h    = (u16*)(ws + 24 * MB);    // LN1 out, later LN2 out
    u16* QKV  = (u16*)(ws + 32 * MB);    // [4096][3072] (V cols unwritten)
    u16* Vtg  = (u16*)(ws + 56 * MB);    // V^T per batch [bb][d][s]
    u16* x2b  = (u16*)(ws + 64 * MB);    // bf16 [4096][1024] = 8MB
    u16* att  = (u16*)(ws + 112 * MB);
    u16* relb = (u16*)(ws + 120 * MB);   // [272][64] bf16 (rows 257+ unread)
    float* bqkv = (float*)(ws + 120 * MB + 128 * 1024);  // 3072 floats
    u16* ff1  = (u16*)(ws + 32 * MB);    // [4096][4096] 32MB aliases QKV+Vtg
    u16* h2   = h;

    dim3 tb(32, 8);
    // prep: weights + relb + bqkv + LN1 (blocks 12365..16460)
    prep_kernel<<<16461, tb, 0, stream>>>(wq, wk, wv, wo, w1, w2, rel,
                                          bq, bk, bv, x, g1, be1,
                                          wqkvT, woT, w1T, w2T, relb, bqkv, h);

    // fused QKV projection; V-column blocks write V^T directly to Vtg
    gemm_bt128k64<<<dim3(24, 32), 256, 0, stream>>>(h, 1024, wqkvT, 1024,
        bqkv, nullptr, QKV, nullptr, 3072, 1024, 1.f, 0, Vtg);

    // attention with fused rel-bias
    attn_kernel<<<1024, 256, 0, stream>>>(QKV, Vtg, relb, att);

    // x2 = x + attn @ wo + bo   (bf16 out)
    gemm_bt64<<<dim3(16, 32), 256, 0, stream>>>(att, 1024, woT, 1024,
        bo, x, nullptr, x2b, nullptr, 1024, 1024, 1.f, 0);

    ln_kernel<<<4096, 256, 0, stream>>>(x2b, g2, be2, h2);

    // ff1 = gelu(h2 @ w1 + b1)  (BM=128, BN=128, BK=64)
    gemm_bt128k64<<<dim3(32, 32), 256, 0, stream>>>(h2, 1024, w1T, 1024,
        bf1, nullptr, ff1, nullptr, 4096, 1024, 1.f, 1, nullptr);
    // out = x2 + ff1 @ w2 + b2  (BK=64, BN=64: 512 blocks, 2/CU)
    gemm_bt64<<<dim3(16, 32), 256, 0, stream>>>(ff1, 4096, w2T, 4096,
        bf2, nullptr, x2b, nullptr, (float*)d_out, 1024, 4096, 1.f, 0);
}